// Round 9
// baseline (660.390 us; speedup 1.0000x reference)
//
#include <hip/hip_runtime.h>
#include <stdint.h>

#define BN   1024
#define FEATN 512
#define HDIM 256
#define TAUF 5.0f
#define EPSF 1e-8f

typedef __attribute__((ext_vector_type(8))) _Float16 half8;
typedef __attribute__((ext_vector_type(4))) float f32x4;

#if defined(__has_builtin)
#if __has_builtin(__builtin_amdgcn_rcpf)
#define HAVE_RCPF 1
#endif
#endif

#ifdef HAVE_RCPF
__device__ __forceinline__ float fast_rcp(float x) { return __builtin_amdgcn_rcpf(x); }
#else
__device__ __forceinline__ float fast_rcp(float x) { return 1.0f / x; }
#endif

// tanh-approx gelu == x * sigmoid(1.5957691x + 0.0713548x^3)
__device__ __forceinline__ float gelu_fast(float x) {
  float s = fmaf(x * x, 0.07135481627f, 1.59576912161f) * x;
  float e = __expf(s);
  return x * e * fast_rcp(e + 1.0f);
}

// ---------------- prep: W1[:512] -> fp16 frag order; label softmax ----------------
__global__ __launch_bounds__(256) void prep_kernel(const float* __restrict__ W1,
                                                   const float* __restrict__ lg,
                                                   _Float16* __restrict__ w1h,
                                                   float* __restrict__ oh) {
  int b = blockIdx.x, t = threadIdx.x;
  if (b < FEATN) {
    int k = b, n = t;
    // B-frag layout: element (k,n) at ((k>>3)*256 + n)*8 + (k&7)
    w1h[(((k >> 3) * HDIM) + n) * 8 + (k & 7)] = (_Float16)W1[k * HDIM + n];
  } else {
    int i = (b - FEATN) * 256 + t;
    float l0 = lg[2 * i], l1 = lg[2 * i + 1];
    float m = fmaxf(l0, l1);
    float e0 = __expf(l0 - m), e1 = __expf(l1 - m);
    float inv = 1.0f / (e0 + e1);
    oh[2 * i] = e0 * inv;
    oh[2 * i + 1] = e1 * inv;
  }
}

// ---------------- main: fused pair-GEMM (fp16 MFMA) + gelu + W2-dot + sigmoid ----------------
// 512 threads = 8 waves, grid 4(m) x 2(n) over the 64-pair x 256-n tile.
// Wave (mg = w&3, ng = w>>2): m-subtile mg (16 pairs) x 8 n-subtiles (128 n).
// acc[8] = 32 AGPR; ~40 arch VGPR -> 6-7 waves/SIMD. Direct construct (2x redundant,
// 1 frag/wave-step), ZERO in-loop barriers, 2 LDS reads/wave-step, stride 528 (<=2-way).
__global__ __launch_bounds__(512, 6) void gemm_kernel(const float* __restrict__ X,
                                                      const _Float16* __restrict__ w1h,
                                                      const float* __restrict__ oh,
                                                      const float* __restrict__ W1,
                                                      const float* __restrict__ b1,
                                                      const float* __restrict__ W2,
                                                      const float* __restrict__ b2,
                                                      float* __restrict__ out_hs) {
  __shared__ __align__(16) _Float16 sX[16 * 528];   // rows 0-7: i, 8-15: j
  __shared__ float sScore[64 * 2];
  __shared__ float sLab0[64], sLab1[64];

  const int tid = threadIdx.x;
  const int L = tid & 63;
  const int w = tid >> 6;              // 0..7
  const int mg = w & 3;                // m-subtile
  const int ng = w >> 2;               // n-half
  const int i0 = blockIdx.y * 8;
  const int j0 = blockIdx.x * 8;

  // ---- stage 16 X rows, f32 -> fp16 (RTNE), LDS stride 528 fp16 ----
  #pragma unroll
  for (int it = 0; it < 2; ++it) {
    int idx = tid + it * 512;          // 1024 octet tasks (16 rows x 64 octets)
    int row = idx >> 6;
    int oc = idx & 63;
    int grow = (row < 8) ? (i0 + row) : (j0 + row - 8);
    const float* gp = X + grow * FEATN + oc * 8;
    float4 a = *(const float4*)gp;
    float4 c = *(const float4*)(gp + 4);
    half8 hv;
    hv[0] = (_Float16)a.x; hv[1] = (_Float16)a.y; hv[2] = (_Float16)a.z; hv[3] = (_Float16)a.w;
    hv[4] = (_Float16)c.x; hv[5] = (_Float16)c.y; hv[6] = (_Float16)c.z; hv[7] = (_Float16)c.w;
    *(half8*)(sX + row * 528 + oc * 8) = hv;
  }
  if (tid < 64) {
    int gi = i0 + (tid >> 3), gj = j0 + (tid & 7);
    sLab0[tid] = oh[2 * gi] * oh[2 * gj];
    sLab1[tid] = oh[2 * gi + 1] * oh[2 * gj + 1];
  }

  // ---- lane decode: pair p = mg*16 + nl; ii = 2mg + (nl>>3); jj = nl&7; koct = L>>4 ----
  const int nl = L & 15;
  const int koct = L >> 4;
  const _Float16* cxi = sX + (2 * mg + (nl >> 3)) * 528 + koct * 8;
  const _Float16* cxj = sX + (8 + (nl & 7)) * 528 + koct * 8;

  // B-frag per-lane base (fp16 elems): step kt at +kt*8192, n-subtile u at +u*128
  const _Float16* bbase = w1h + ((koct * HDIM) + ng * 128 + nl) * 8;

  f32x4 acc[8];
  #pragma unroll
  for (int u = 0; u < 8; ++u) acc[u] = (f32x4){0.f, 0.f, 0.f, 0.f};

  __syncthreads();

  #pragma unroll 2
  for (int kt = 0; kt < 16; ++kt) {
    // A-frag: 2 broadcast LDS reads + pk-sub + abs (8 VALU)
    half8 xi = *(const half8*)(cxi + kt * 32);
    half8 xj = *(const half8*)(cxj + kt * 32);
    union { half8 h; unsigned u4[4]; } A;
    A.h = xi - xj;
    A.u4[0] &= 0x7FFF7FFFu; A.u4[1] &= 0x7FFF7FFFu;
    A.u4[2] &= 0x7FFF7FFFu; A.u4[3] &= 0x7FFF7FFFu;

    // B-frags (unique per wave): 2 batches of 4 x 16B from L1/L2
    const _Float16* bs = bbase + kt * 8192;
    #pragma unroll
    for (int h = 0; h < 2; ++h) {
      half8 bfr[4];
      #pragma unroll
      for (int u = 0; u < 4; ++u)
        bfr[u] = *(const half8*)(bs + h * 512 + u * 128);
      #pragma unroll
      for (int u = 0; u < 4; ++u)
        acc[h * 4 + u] = __builtin_amdgcn_mfma_f32_16x16x32_f16(A.h, bfr[u], acc[h * 4 + u], 0, 0, 0);
    }
  }

  // ---- epilogue: + label rank-2 + b1, fast gelu, dot W2 over 128 n, reduce ----
  const int q = L >> 4;
  #pragma unroll
  for (int r = 0; r < 4; ++r) {
    int p = mg * 16 + q * 4 + r;       // C/D: row = quad*4 + reg
    float l0v = sLab0[p], l1v = sLab1[p];
    float v = 0.f;
    #pragma unroll
    for (int u = 0; u < 8; ++u) {
      int n = ng * 128 + u * 16 + nl;
      float e = acc[u][r] + l0v * W1[512 * HDIM + n] + l1v * W1[513 * HDIM + n] + b1[n];
      v += gelu_fast(e) * W2[n];
    }
    v += __shfl_xor(v, 1, 64);
    v += __shfl_xor(v, 2, 64);
    v += __shfl_xor(v, 4, 64);
    v += __shfl_xor(v, 8, 64);         // sum over the 16 nl lanes
    if (nl == 0) sScore[p * 2 + ng] = v;
  }
  __syncthreads();
  if (tid < 64) {
    float s2 = sScore[tid * 2] + sScore[tid * 2 + 1] + b2[0];
    float hsv = fast_rcp(1.0f + __expf(-s2));
    int gi = i0 + (tid >> 3), gj = j0 + (tid & 7);
    out_hs[(size_t)gi * BN + gj] = hsv;
  }
}

// ---------------- row softmax of adj + TAU*log(hs + EPS) ----------------
__global__ __launch_bounds__(256) void softmax_kernel(const float* __restrict__ adj,
                                                      const float* __restrict__ hs,
                                                      float* __restrict__ out) {
  int i = blockIdx.x, t = threadIdx.x;
  __shared__ float redm[4];
  __shared__ float reds[4];
  float l[4];
  float mx = -1e30f;
  #pragma unroll
  for (int k = 0; k < 4; ++k) {
    int j = t + k * 256;
    float lv = adj[(size_t)i * BN + j] + TAUF * __logf(hs[(size_t)i * BN + j] + EPSF);
    l[k] = lv;
    mx = fmaxf(mx, lv);
  }
  #pragma unroll
  for (int o = 1; o <= 32; o <<= 1) mx = fmaxf(mx, __shfl_xor(mx, o, 64));
  if ((t & 63) == 0) redm[t >> 6] = mx;
  __syncthreads();
  mx = fmaxf(fmaxf(redm[0], redm[1]), fmaxf(redm[2], redm[3]));
  float ex[4];
  float se = 0.f;
  #pragma unroll
  for (int k = 0; k < 4; ++k) { ex[k] = __expf(l[k] - mx); se += ex[k]; }
  #pragma unroll
  for (int o = 1; o <= 32; o <<= 1) se += __shfl_xor(se, o, 64);
  if ((t & 63) == 0) reds[t >> 6] = se;
  __syncthreads();
  se = reds[0] + reds[1] + reds[2] + reds[3];
  float inv = fast_rcp(se);
  #pragma unroll
  for (int k = 0; k < 4; ++k) out[(size_t)i * BN + t + k * 256] = ex[k] * inv;
}

extern "C" void kernel_launch(void* const* d_in, const int* in_sizes, int n_in,
                              void* d_out, int out_size, void* d_ws, size_t ws_size,
                              hipStream_t stream) {
  (void)in_sizes; (void)n_in; (void)out_size; (void)ws_size;
  const float* X   = (const float*)d_in[0];
  const float* lg  = (const float*)d_in[1];
  const float* adj = (const float*)d_in[2];
  const float* W1  = (const float*)d_in[3];
  const float* b1  = (const float*)d_in[4];
  const float* W2  = (const float*)d_in[5];
  const float* b2  = (const float*)d_in[6];
  float* out = (float*)d_out;                       // [0,B^2): adj_refined, [B^2,2B^2): h_scores
  _Float16* w1h = (_Float16*)d_ws;                  // 512*256 fp16 = 256 KB
  float* oh = (float*)((char*)d_ws + FEATN * HDIM * 2);  // 1024*2 f32

  float* out_hs = out + (size_t)BN * BN;

  prep_kernel<<<dim3(FEATN + 4), dim3(256), 0, stream>>>(W1, lg, w1h, oh);
  gemm_kernel<<<dim3(128, 128), dim3(512), 0, stream>>>(X, w1h, oh, W1, b1, W2, b2, out_hs);
  softmax_kernel<<<dim3(BN), dim3(256), 0, stream>>>(adj, out_hs, out);
}

// Round 10
// 457.227 us; speedup vs baseline: 1.4443x; 1.4443x over previous
//
#include <hip/hip_runtime.h>
#include <stdint.h>

#define BN   1024
#define FEATN 512
#define HDIM 256
#define TAUF 5.0f
#define EPSF 1e-8f

typedef __attribute__((ext_vector_type(8))) _Float16 half8;
typedef __attribute__((ext_vector_type(16))) float f32x16;

#if defined(__has_builtin)
#if __has_builtin(__builtin_amdgcn_rcpf)
#define HAVE_RCPF 1
#endif
#endif

#ifdef HAVE_RCPF
__device__ __forceinline__ float fast_rcp(float x) { return __builtin_amdgcn_rcpf(x); }
#else
__device__ __forceinline__ float fast_rcp(float x) { return 1.0f / x; }
#endif

// tanh-approx gelu == x * sigmoid(1.5957691x + 0.0713548x^3)
__device__ __forceinline__ float gelu_fast(float x) {
  float s = fmaf(x * x, 0.07135481627f, 1.59576912161f) * x;
  float e = __expf(s);
  return x * e * fast_rcp(e + 1.0f);
}

// ---------------- prep: W1[:512] -> fp16 32x32x16 B-frag order; label softmax ----------------
// B-frag (mfma_f32_32x32x16_f16): lane = (n&31) + 32*((k>>3)&1), j = k&7, k-step ks = k>>4,
// n-subtile u32 = n>>5.  Element (k,n) stored at ((ks*8 + u32)*64 + lane)*8 + j.
__global__ __launch_bounds__(256) void prep_kernel(const float* __restrict__ W1,
                                                   const float* __restrict__ lg,
                                                   _Float16* __restrict__ w1h,
                                                   float* __restrict__ oh) {
  int b = blockIdx.x, t = threadIdx.x;
  if (b < FEATN) {
    int k = b, n = t;
    int ks = k >> 4, j = k & 7, half = (k >> 3) & 1;
    int lane = (n & 31) + 32 * half;
    int u32 = n >> 5;
    w1h[(((ks * 8 + u32) * 64) + lane) * 8 + j] = (_Float16)W1[k * HDIM + n];
  } else {
    int i = (b - FEATN) * 256 + t;
    float l0 = lg[2 * i], l1 = lg[2 * i + 1];
    float m = fmaxf(l0, l1);
    float e0 = __expf(l0 - m), e1 = __expf(l1 - m);
    float inv = 1.0f / (e0 + e1);
    oh[2 * i] = e0 * inv;
    oh[2 * i + 1] = e1 * inv;
  }
}

// ---------------- main: fused pair-GEMM (32x32x16 fp16 MFMA) + gelu + W2-dot + sigmoid -------
// Tile: 64 pairs (8i x 8j) x 256 n; 4 waves split n (64 n each; B-issue redundancy 1 --
// the R9 lesson). A-frags shared via double-buffered sA: per K=32 chunk, wave w constructs
// the frag for (k-substep w>>1, m-subtile w&1) -> construct-once, 1 barrier/chunk.
// acc[2][2] f32x16 = 64 AGPR; 32x32 shape: matrix -17% cyc, MFMA slots halved vs 16x16.
__global__ __launch_bounds__(256, 4) void gemm_kernel(const float* __restrict__ X,
                                                      const _Float16* __restrict__ w1h,
                                                      const float* __restrict__ oh,
                                                      const float* __restrict__ W1,
                                                      const float* __restrict__ b1,
                                                      const float* __restrict__ W2,
                                                      const float* __restrict__ b2,
                                                      float* __restrict__ out_hs) {
  __shared__ __align__(16) _Float16 sX[16 * 528];   // rows 0-7: i, 8-15: j
  __shared__ __align__(16) half8 sA[2][2][2][64];   // [buf][substep][m-subtile][lane]
  __shared__ float sScore[64 * 4];
  __shared__ float sLab0[64], sLab1[64];

  const int tid = threadIdx.x;
  const int L = tid & 63;
  const int w = tid >> 6;              // wave id == n-quarter (64 n)
  const int i0 = blockIdx.y * 8;
  const int j0 = blockIdx.x * 8;

  // ---- stage 16 X rows, f32 -> fp16 (RTNE), LDS stride 528 fp16 (0 conflicts @ R9) ----
  #pragma unroll
  for (int it = 0; it < 4; ++it) {
    int idx = tid + it * 256;          // 1024 octet tasks
    int row = idx >> 6;
    int oc = idx & 63;
    int grow = (row < 8) ? (i0 + row) : (j0 + row - 8);
    const float* gp = X + grow * FEATN + oc * 8;
    float4 a = *(const float4*)gp;
    float4 c = *(const float4*)(gp + 4);
    half8 hv;
    hv[0] = (_Float16)a.x; hv[1] = (_Float16)a.y; hv[2] = (_Float16)a.z; hv[3] = (_Float16)a.w;
    hv[4] = (_Float16)c.x; hv[5] = (_Float16)c.y; hv[6] = (_Float16)c.z; hv[7] = (_Float16)c.w;
    *(half8*)(sX + row * 528 + oc * 8) = hv;
  }
  if (tid < 64) {
    int gi = i0 + (tid >> 3), gj = j0 + (tid & 7);
    sLab0[tid] = oh[2 * gi] * oh[2 * gj];
    sLab1[tid] = oh[2 * gi + 1] * oh[2 * gj + 1];
  }

  // ---- construct decode: wave w builds frag (substep ct=w>>1, m-subtile cs=w&1) ----
  // A-frag (32x32x16): lane L holds A[m = L&31][k = (L>>5)*8 + j]. pair p = cs*32 + (L&31);
  // ii = p>>3 = cs*4 + ((L&31)>>3); jj = p&7 = L&7.
  const int l31 = L & 31;
  const int cs = w & 1;
  const int ct = w >> 1;
  const _Float16* cxi = sX + (cs * 4 + (l31 >> 3)) * 528 + ct * 16 + (L >> 5) * 8;
  const _Float16* cxj = sX + (8 + (L & 7)) * 528 + ct * 16 + (L >> 5) * 8;

  // ---- B base (fp16 elems): chunk kt at +kt*8192, substep t at +t*4096, local u at +u*512 ----
  const _Float16* bbase = w1h + 2 * w * 512 + L * 8;

  f32x16 acc[2][2];
  #pragma unroll
  for (int s = 0; s < 2; ++s)
    #pragma unroll
    for (int u = 0; u < 2; ++u)
      #pragma unroll
      for (int r = 0; r < 16; ++r) acc[s][u][r] = 0.f;

  __syncthreads();

  #define CONSTRUCT(kt, buf)                                              \
    {                                                                     \
      half8 xi = *(const half8*)(cxi + (kt) * 32);                        \
      half8 xj = *(const half8*)(cxj + (kt) * 32);                        \
      union { half8 h; unsigned u4[4]; } U;                               \
      U.h = xi - xj;                                                      \
      U.u4[0] &= 0x7FFF7FFFu; U.u4[1] &= 0x7FFF7FFFu;                     \
      U.u4[2] &= 0x7FFF7FFFu; U.u4[3] &= 0x7FFF7FFFu;                     \
      sA[buf][ct][cs][L] = U.h;                                           \
    }

  // prologue
  CONSTRUCT(0, 0)
  __syncthreads();

  #pragma unroll 2
  for (int kt = 0; kt < 16; ++kt) {
    const int buf = kt & 1;
    // B frags for this chunk (unique per wave; coalesced 16B/lane)
    half8 bfr[2][2];
    #pragma unroll
    for (int t = 0; t < 2; ++t)
      #pragma unroll
      for (int u = 0; u < 2; ++u)
        bfr[t][u] = *(const half8*)(bbase + kt * 8192 + t * 4096 + u * 512);
    // A frags from shared
    half8 afr[2][2];
    #pragma unroll
    for (int t = 0; t < 2; ++t)
      #pragma unroll
      for (int s = 0; s < 2; ++s)
        afr[t][s] = sA[buf][t][s][L];
    // construct next chunk into the other buffer (no hazard: opposite buf)
    if (kt < 15) CONSTRUCT(kt + 1, 1 - buf)
    #pragma unroll
    for (int t = 0; t < 2; ++t)
      #pragma unroll
      for (int s = 0; s < 2; ++s)
        #pragma unroll
        for (int u = 0; u < 2; ++u)
          acc[s][u] = __builtin_amdgcn_mfma_f32_32x32x16_f16(afr[t][s], bfr[t][u], acc[s][u], 0, 0, 0);
    __syncthreads();
  }
  #undef CONSTRUCT

  // ---- epilogue: + label rank-2 + b1, fast gelu, dot W2, reduce, sigmoid ----
  // C/D (32x32): n-col = w*64 + u*32 + (L&31); pair-row = s*32 + (r&3) + 8*(r>>2) + 4*(L>>5).
  float w2v[2], a0v[2], a1v[2], bbv[2];
  #pragma unroll
  for (int u = 0; u < 2; ++u) {
    int n = w * 64 + u * 32 + l31;
    a0v[u] = W1[512 * HDIM + n];
    a1v[u] = W1[513 * HDIM + n];
    bbv[u] = b1[n];
    w2v[u] = W2[n];
  }
  #pragma unroll
  for (int s = 0; s < 2; ++s) {
    #pragma unroll
    for (int r = 0; r < 16; ++r) {
      int p = s * 32 + (r & 3) + 8 * (r >> 2) + 4 * (L >> 5);
      float l0v = sLab0[p], l1v = sLab1[p];
      float v = 0.f;
      #pragma unroll
      for (int u = 0; u < 2; ++u) {
        float e = acc[s][u][r] + l0v * a0v[u] + l1v * a1v[u] + bbv[u];
        v += gelu_fast(e) * w2v[u];
      }
      v += __shfl_xor(v, 1, 64);
      v += __shfl_xor(v, 2, 64);
      v += __shfl_xor(v, 4, 64);
      v += __shfl_xor(v, 8, 64);
      v += __shfl_xor(v, 16, 64);      // sum over the 32 (L&31) lanes
      if (l31 == 0) sScore[p * 4 + w] = v;
    }
  }
  __syncthreads();
  if (tid < 64) {
    float s4 = sScore[tid * 4 + 0] + sScore[tid * 4 + 1] + sScore[tid * 4 + 2] +
               sScore[tid * 4 + 3] + b2[0];
    float hsv = fast_rcp(1.0f + __expf(-s4));
    int gi = i0 + (tid >> 3), gj = j0 + (tid & 7);
    out_hs[(size_t)gi * BN + gj] = hsv;
  }
}

// ---------------- row softmax of adj + TAU*log(hs + EPS) ----------------
__global__ __launch_bounds__(256) void softmax_kernel(const float* __restrict__ adj,
                                                      const float* __restrict__ hs,
                                                      float* __restrict__ out) {
  int i = blockIdx.x, t = threadIdx.x;
  __shared__ float redm[4];
  __shared__ float reds[4];
  float l[4];
  float mx = -1e30f;
  #pragma unroll
  for (int k = 0; k < 4; ++k) {
    int j = t + k * 256;
    float lv = adj[(size_t)i * BN + j] + TAUF * __logf(hs[(size_t)i * BN + j] + EPSF);
    l[k] = lv;
    mx = fmaxf(mx, lv);
  }
  #pragma unroll
  for (int o = 1; o <= 32; o <<= 1) mx = fmaxf(mx, __shfl_xor(mx, o, 64));
  if ((t & 63) == 0) redm[t >> 6] = mx;
  __syncthreads();
  mx = fmaxf(fmaxf(redm[0], redm[1]), fmaxf(redm[2], redm[3]));
  float ex[4];
  float se = 0.f;
  #pragma unroll
  for (int k = 0; k < 4; ++k) { ex[k] = __expf(l[k] - mx); se += ex[k]; }
  #pragma unroll
  for (int o = 1; o <= 32; o <<= 1) se += __shfl_xor(se, o, 64);
  if ((t & 63) == 0) reds[t >> 6] = se;
  __syncthreads();
  se = reds[0] + reds[1] + reds[2] + reds[3];
  float inv = fast_rcp(se);
  #pragma unroll
  for (int k = 0; k < 4; ++k) out[(size_t)i * BN + t + k * 256] = ex[k] * inv;
}

extern "C" void kernel_launch(void* const* d_in, const int* in_sizes, int n_in,
                              void* d_out, int out_size, void* d_ws, size_t ws_size,
                              hipStream_t stream) {
  (void)in_sizes; (void)n_in; (void)out_size; (void)ws_size;
  const float* X   = (const float*)d_in[0];
  const float* lg  = (const float*)d_in[1];
  const float* adj = (const float*)d_in[2];
  const float* W1  = (const float*)d_in[3];
  const float* b1  = (const float*)d_in[4];
  const float* W2  = (const float*)d_in[5];
  const float* b2  = (const float*)d_in[6];
  float* out = (float*)d_out;                       // [0,B^2): adj_refined, [B^2,2B^2): h_scores
  _Float16* w1h = (_Float16*)d_ws;                  // 512*256 fp16 = 256 KB
  float* oh = (float*)((char*)d_ws + FEATN * HDIM * 2);  // 1024*2 f32

  float* out_hs = out + (size_t)BN * BN;

  prep_kernel<<<dim3(FEATN + 4), dim3(256), 0, stream>>>(W1, lg, w1h, oh);
  gemm_kernel<<<dim3(128, 128), dim3(256), 0, stream>>>(X, w1h, oh, W1, b1, W2, b2, out_hs);
  softmax_kernel<<<dim3(BN), dim3(256), 0, stream>>>(adj, out_hs, out);
}

// Round 11
// 446.165 us; speedup vs baseline: 1.4801x; 1.0248x over previous
//
#include <hip/hip_runtime.h>
#include <stdint.h>

#define BN   1024
#define FEATN 512
#define HDIM 256
#define TAUF 5.0f
#define EPSF 1e-8f

typedef __attribute__((ext_vector_type(8))) _Float16 half8;
typedef __attribute__((ext_vector_type(4))) float f32x4;

#if defined(__has_builtin)
#if __has_builtin(__builtin_amdgcn_rcpf)
#define HAVE_RCPF 1
#endif
#endif

#ifdef HAVE_RCPF
__device__ __forceinline__ float fast_rcp(float x) { return __builtin_amdgcn_rcpf(x); }
#else
__device__ __forceinline__ float fast_rcp(float x) { return 1.0f / x; }
#endif

// tanh-approx gelu == x * sigmoid(1.5957691x + 0.0713548x^3)
__device__ __forceinline__ float gelu_fast(float x) {
  float s = fmaf(x * x, 0.07135481627f, 1.59576912161f) * x;
  float e = __expf(s);
  return x * e * fast_rcp(e + 1.0f);
}

// ---------------- prep: W1[:512] -> fp16 16x16x32 B-frag order; label softmax ----------------
__global__ __launch_bounds__(256) void prep_kernel(const float* __restrict__ W1,
                                                   const float* __restrict__ lg,
                                                   _Float16* __restrict__ w1h,
                                                   float* __restrict__ oh) {
  int b = blockIdx.x, t = threadIdx.x;
  if (b < FEATN) {
    int k = b, n = t;
    // B-frag layout: element (k,n) at ((k>>3)*256 + n)*8 + (k&7)
    w1h[(((k >> 3) * HDIM) + n) * 8 + (k & 7)] = (_Float16)W1[k * HDIM + n];
  } else {
    int i = (b - FEATN) * 256 + t;
    float l0 = lg[2 * i], l1 = lg[2 * i + 1];
    float m = fmaxf(l0, l1);
    float e0 = __expf(l0 - m), e1 = __expf(l1 - m);
    float inv = 1.0f / (e0 + e1);
    oh[2 * i] = e0 * inv;
    oh[2 * i + 1] = e1 * inv;
  }
}

// ---------------- main: fused pair-GEMM (fp16 MFMA) + gelu + W2-dot + sigmoid ----------------
// Tile: 64 pairs (8i x 8j) x 256 n. Wave grid 2(m) x 2(n): wave = 32 pairs x 128 n.
// The (2x construct, 2x B-issue) point of the redundancy design space:
//   - each wave constructs its own 2 m-subtile A-frags (16 VALU/step, below matrix budget)
//   - each n-half's B read twice per block (32 KB/block-step, below the R9 failure level)
//   - ZERO K-loop barriers, no sA round-trip (R7's stall sources gone)
// acc[2][8] = 64 AGPR + ~50 arch VGPR -> 4 waves/SIMD, 4 blocks/CU.
__global__ __launch_bounds__(256, 4) void gemm_kernel(const float* __restrict__ X,
                                                      const _Float16* __restrict__ w1h,
                                                      const float* __restrict__ oh,
                                                      const float* __restrict__ W1,
                                                      const float* __restrict__ b1,
                                                      const float* __restrict__ W2,
                                                      const float* __restrict__ b2,
                                                      float* __restrict__ out_hs) {
  __shared__ __align__(16) _Float16 sX[16 * 528];   // rows 0-7: i, 8-15: j (stride 528: 0 conflicts)
  __shared__ float sScore[64 * 2];
  __shared__ float sLab0[64], sLab1[64];

  const int tid = threadIdx.x;
  const int L = tid & 63;
  const int w = tid >> 6;              // 0..3
  const int mg = w & 1;                // m-half (pairs 32mg..32mg+31 = subtiles 2mg,2mg+1)
  const int ng = w >> 1;               // n-half (subtiles 8ng..8ng+7)
  const int i0 = blockIdx.y * 8;
  const int j0 = blockIdx.x * 8;

  // ---- stage 16 X rows, f32 -> fp16 (RTNE), LDS stride 528 fp16 ----
  #pragma unroll
  for (int it = 0; it < 4; ++it) {
    int idx = tid + it * 256;          // 1024 octet tasks
    int row = idx >> 6;
    int oc = idx & 63;
    int grow = (row < 8) ? (i0 + row) : (j0 + row - 8);
    const float* gp = X + grow * FEATN + oc * 8;
    float4 a = *(const float4*)gp;
    float4 c = *(const float4*)(gp + 4);
    half8 hv;
    hv[0] = (_Float16)a.x; hv[1] = (_Float16)a.y; hv[2] = (_Float16)a.z; hv[3] = (_Float16)a.w;
    hv[4] = (_Float16)c.x; hv[5] = (_Float16)c.y; hv[6] = (_Float16)c.z; hv[7] = (_Float16)c.w;
    *(half8*)(sX + row * 528 + oc * 8) = hv;
  }
  if (tid < 64) {
    int gi = i0 + (tid >> 3), gj = j0 + (tid & 7);
    sLab0[tid] = oh[2 * gi] * oh[2 * gj];
    sLab1[tid] = oh[2 * gi + 1] * oh[2 * gj + 1];
  }

  // ---- lane decode: subtile s = 2mg+t, pair p = 16s + nl; ii = 2s + (nl>>3); jj = nl&7 ----
  const int nl = L & 15;
  const int koct = L >> 4;
  const _Float16* cxi0 = sX + (4 * mg + (nl >> 3)) * 528 + koct * 8;   // t=0
  const _Float16* cxi1 = cxi0 + 2 * 528;                                // t=1
  const _Float16* cxj  = sX + (8 + (nl & 7)) * 528 + koct * 8;

  // B-frag per-lane base (fp16 elems): step kt at +kt*8192, local n-subtile u at +u*128
  const _Float16* bbase = w1h + ((koct * HDIM) + ng * 128 + nl) * 8;

  f32x4 acc[2][8];
  #pragma unroll
  for (int t = 0; t < 2; ++t)
    #pragma unroll
    for (int u = 0; u < 8; ++u) acc[t][u] = (f32x4){0.f, 0.f, 0.f, 0.f};

  __syncthreads();

  #pragma unroll 2
  for (int kt = 0; kt < 16; ++kt) {
    // A-frags: 3 broadcast LDS reads + 2x (pk-sub + abs) = 16 VALU
    half8 xj  = *(const half8*)(cxj  + kt * 32);
    half8 xi0 = *(const half8*)(cxi0 + kt * 32);
    half8 xi1 = *(const half8*)(cxi1 + kt * 32);
    union { half8 h; unsigned u4[4]; } A0, A1;
    A0.h = xi0 - xj;
    A1.h = xi1 - xj;
    A0.u4[0] &= 0x7FFF7FFFu; A0.u4[1] &= 0x7FFF7FFFu;
    A0.u4[2] &= 0x7FFF7FFFu; A0.u4[3] &= 0x7FFF7FFFu;
    A1.u4[0] &= 0x7FFF7FFFu; A1.u4[1] &= 0x7FFF7FFFu;
    A1.u4[2] &= 0x7FFF7FFFu; A1.u4[3] &= 0x7FFF7FFFu;

    // B-frags for this wave's n-half: 2 batches of 4 x 16B (imm offsets)
    const _Float16* bs = bbase + kt * 8192;
    #pragma unroll
    for (int h = 0; h < 2; ++h) {
      half8 bfr[4];
      #pragma unroll
      for (int u = 0; u < 4; ++u)
        bfr[u] = *(const half8*)(bs + h * 512 + u * 128);
      #pragma unroll
      for (int u = 0; u < 4; ++u) {
        acc[0][h * 4 + u] = __builtin_amdgcn_mfma_f32_16x16x32_f16(A0.h, bfr[u], acc[0][h * 4 + u], 0, 0, 0);
        acc[1][h * 4 + u] = __builtin_amdgcn_mfma_f32_16x16x32_f16(A1.h, bfr[u], acc[1][h * 4 + u], 0, 0, 0);
      }
    }
  }

  // ---- epilogue: + label rank-2 + b1, fast gelu, dot W2 over this n-half, reduce ----
  const int q = L >> 4;
  float w1l0[8], w1l1[8], bb1[8], ww2[8];
  #pragma unroll
  for (int u = 0; u < 8; ++u) {
    int n = ng * 128 + u * 16 + nl;
    w1l0[u] = W1[512 * HDIM + n];
    w1l1[u] = W1[513 * HDIM + n];
    bb1[u] = b1[n];
    ww2[u] = W2[n];
  }
  #pragma unroll
  for (int t = 0; t < 2; ++t) {
    #pragma unroll
    for (int r = 0; r < 4; ++r) {
      int p = (2 * mg + t) * 16 + q * 4 + r;   // C/D: row = quad*4 + reg
      float l0v = sLab0[p], l1v = sLab1[p];
      float v = 0.f;
      #pragma unroll
      for (int u = 0; u < 8; ++u) {
        float e = acc[t][u][r] + l0v * w1l0[u] + l1v * w1l1[u] + bb1[u];
        v += gelu_fast(e) * ww2[u];
      }
      v += __shfl_xor(v, 1, 64);
      v += __shfl_xor(v, 2, 64);
      v += __shfl_xor(v, 4, 64);
      v += __shfl_xor(v, 8, 64);       // sum over the 16 nl lanes
      if (nl == 0) sScore[p * 2 + ng] = v;
    }
  }
  __syncthreads();
  if (tid < 64) {
    float s2 = sScore[tid * 2] + sScore[tid * 2 + 1] + b2[0];
    float hsv = fast_rcp(1.0f + __expf(-s2));
    int gi = i0 + (tid >> 3), gj = j0 + (tid & 7);
    out_hs[(size_t)gi * BN + gj] = hsv;
  }
}

// ---------------- row softmax of adj + TAU*log(hs + EPS) ----------------
__global__ __launch_bounds__(256) void softmax_kernel(const float* __restrict__ adj,
                                                      const float* __restrict__ hs,
                                                      float* __restrict__ out) {
  int i = blockIdx.x, t = threadIdx.x;
  __shared__ float redm[4];
  __shared__ float reds[4];
  float l[4];
  float mx = -1e30f;
  #pragma unroll
  for (int k = 0; k < 4; ++k) {
    int j = t + k * 256;
    float lv = adj[(size_t)i * BN + j] + TAUF * __logf(hs[(size_t)i * BN + j] + EPSF);
    l[k] = lv;
    mx = fmaxf(mx, lv);
  }
  #pragma unroll
  for (int o = 1; o <= 32; o <<= 1) mx = fmaxf(mx, __shfl_xor(mx, o, 64));
  if ((t & 63) == 0) redm[t >> 6] = mx;
  __syncthreads();
  mx = fmaxf(fmaxf(redm[0], redm[1]), fmaxf(redm[2], redm[3]));
  float ex[4];
  float se = 0.f;
  #pragma unroll
  for (int k = 0; k < 4; ++k) { ex[k] = __expf(l[k] - mx); se += ex[k]; }
  #pragma unroll
  for (int o = 1; o <= 32; o <<= 1) se += __shfl_xor(se, o, 64);
  if ((t & 63) == 0) reds[t >> 6] = se;
  __syncthreads();
  se = reds[0] + reds[1] + reds[2] + reds[3];
  float inv = fast_rcp(se);
  #pragma unroll
  for (int k = 0; k < 4; ++k) out[(size_t)i * BN + t + k * 256] = ex[k] * inv;
}

extern "C" void kernel_launch(void* const* d_in, const int* in_sizes, int n_in,
                              void* d_out, int out_size, void* d_ws, size_t ws_size,
                              hipStream_t stream) {
  (void)in_sizes; (void)n_in; (void)out_size; (void)ws_size;
  const float* X   = (const float*)d_in[0];
  const float* lg  = (const float*)d_in[1];
  const float* adj = (const float*)d_in[2];
  const float* W1  = (const float*)d_in[3];
  const float* b1  = (const float*)d_in[4];
  const float* W2  = (const float*)d_in[5];
  const float* b2  = (const float*)d_in[6];
  float* out = (float*)d_out;                       // [0,B^2): adj_refined, [B^2,2B^2): h_scores
  _Float16* w1h = (_Float16*)d_ws;                  // 512*256 fp16 = 256 KB
  float* oh = (float*)((char*)d_ws + FEATN * HDIM * 2);  // 1024*2 f32

  float* out_hs = out + (size_t)BN * BN;

  prep_kernel<<<dim3(FEATN + 4), dim3(256), 0, stream>>>(W1, lg, w1h, oh);
  gemm_kernel<<<dim3(128, 128), dim3(256), 0, stream>>>(X, w1h, oh, W1, b1, W2, b2, out_hs);
  softmax_kernel<<<dim3(BN), dim3(256), 0, stream>>>(adj, out_hs, out);
}

// Round 12
// 417.751 us; speedup vs baseline: 1.5808x; 1.0680x over previous
//
#include <hip/hip_runtime.h>
#include <stdint.h>

#define BN   1024
#define FEATN 512
#define HDIM 256
#define TAUF 5.0f
#define EPSF 1e-8f

typedef __attribute__((ext_vector_type(8))) _Float16 half8;
typedef __attribute__((ext_vector_type(4))) float f32x4;

#if defined(__has_builtin)
#if __has_builtin(__builtin_amdgcn_rcpf)
#define HAVE_RCPF 1
#endif
#endif

#ifdef HAVE_RCPF
__device__ __forceinline__ float fast_rcp(float x) { return __builtin_amdgcn_rcpf(x); }
#else
__device__ __forceinline__ float fast_rcp(float x) { return 1.0f / x; }
#endif

// tanh-approx gelu == x * sigmoid(1.5957691x + 0.0713548x^3)
__device__ __forceinline__ float gelu_fast(float x) {
  float s = fmaf(x * x, 0.07135481627f, 1.59576912161f) * x;
  float e = __expf(s);
  return x * e * fast_rcp(e + 1.0f);
}

// ---------------- prep: W1[:512] -> fp16 frag order (coalesced); label softmax ----------------
// Block b<64 = k-octet: thread t = n reads W1[(8b+j)*256+t] (8 coalesced row-reads) and
// writes ONE contiguous half8 at w1h[(b*256+t)*8] -- 16 B/lane coalesced store
// (replaces the 2 B/lane stride-16 scatter that dominated the prep time).
__global__ __launch_bounds__(256) void prep_kernel(const float* __restrict__ W1,
                                                   const float* __restrict__ lg,
                                                   _Float16* __restrict__ w1h,
                                                   float* __restrict__ oh) {
  int b = blockIdx.x, t = threadIdx.x;
  if (b < 64) {
    half8 hv;
    #pragma unroll
    for (int j = 0; j < 8; ++j)
      hv[j] = (_Float16)W1[(b * 8 + j) * HDIM + t];
    // B-frag layout: element (k,n) at ((k>>3)*256 + n)*8 + (k&7)
    *(half8*)(w1h + ((b * HDIM) + t) * 8) = hv;
  } else {
    int i = (b - 64) * 256 + t;        // 4 blocks * 256 = 1024
    float l0 = lg[2 * i], l1 = lg[2 * i + 1];
    float m = fmaxf(l0, l1);
    float e0 = __expf(l0 - m), e1 = __expf(l1 - m);
    float inv = 1.0f / (e0 + e1);
    oh[2 * i] = e0 * inv;
    oh[2 * i + 1] = e1 * inv;
  }
}

// ---------------- main: fused pair-GEMM (fp16 MFMA) + gelu + W2-dot + sigmoid ----------------
// The R7-proven structure (best of 11 structural variants): tile 64 pairs x 256 n,
// waves split n (B-issue redundancy 1), A-frags construct-once shared via double-buffered
// sA in 2-step chunks (1 barrier / 2 k-steps). Change vs R7: sX stride 520 -> 528
// (bank = (8r+4c) mod 32, provably distinct -> 0 conflicts, confirmed by R9/R11 PMC).
__global__ __launch_bounds__(256, 4) void gemm_kernel(const float* __restrict__ X,
                                                      const _Float16* __restrict__ w1h,
                                                      const float* __restrict__ oh,
                                                      const float* __restrict__ W1,
                                                      const float* __restrict__ b1,
                                                      const float* __restrict__ W2,
                                                      const float* __restrict__ b2,
                                                      float* __restrict__ out_hs) {
  __shared__ __align__(16) _Float16 sX[16 * 528];     // rows 0-7: i, 8-15: j
  __shared__ __align__(16) half8 sA[2][2][4][64];     // [buf][step-in-chunk][m-subtile][lane]
  __shared__ float sScore[64 * 4];
  __shared__ float sLab0[64], sLab1[64];

  const int tid = threadIdx.x;
  const int L = tid & 63;
  const int w = tid >> 6;              // wave id == n-quarter AND construct m-subtile
  const int i0 = blockIdx.y * 8;
  const int j0 = blockIdx.x * 8;

  // ---- stage 16 X rows, f32 -> fp16 (RTNE), LDS stride 528 fp16 ----
  #pragma unroll
  for (int it = 0; it < 4; ++it) {
    int idx = tid + it * 256;          // 1024 octet tasks (16 rows x 64 octets)
    int row = idx >> 6;
    int oc = idx & 63;
    int grow = (row < 8) ? (i0 + row) : (j0 + row - 8);
    const float* gp = X + grow * FEATN + oc * 8;
    float4 a = *(const float4*)gp;
    float4 c = *(const float4*)(gp + 4);
    half8 hv;
    hv[0] = (_Float16)a.x; hv[1] = (_Float16)a.y; hv[2] = (_Float16)a.z; hv[3] = (_Float16)a.w;
    hv[4] = (_Float16)c.x; hv[5] = (_Float16)c.y; hv[6] = (_Float16)c.z; hv[7] = (_Float16)c.w;
    *(half8*)(sX + row * 528 + oc * 8) = hv;
  }
  if (tid < 64) {
    int gi = i0 + (tid >> 3), gj = j0 + (tid & 7);
    sLab0[tid] = oh[2 * gi] * oh[2 * gj];
    sLab1[tid] = oh[2 * gi + 1] * oh[2 * gj + 1];
  }

  // ---- construct decode: wave w builds m-subtile w's frag for lane L ----
  // pair m = 16w + (L&15); ii = 2w + ((L&15)>>3); jj = L&7; koct = L>>4
  const int nl = L & 15;
  const int koct = L >> 4;
  const _Float16* cxi = sX + (2 * w + (nl >> 3)) * 528 + koct * 8;
  const _Float16* cxj = sX + (8 + (L & 7)) * 528 + koct * 8;

  // B-frag per-lane base (fp16 elems): step kt at +kt*8192, n-subtile u at +u*128
  const _Float16* bbase = w1h + ((koct * HDIM) + w * 64 + nl) * 8;

  f32x4 acc[4][4];
  #pragma unroll
  for (int s = 0; s < 4; ++s)
    #pragma unroll
    for (int u = 0; u < 4; ++u) acc[s][u] = (f32x4){0.f, 0.f, 0.f, 0.f};

  __syncthreads();

  // construct one step's A-frag (fp16 pk-sub + abs mask) into sA[buf][st]
  #define CONSTRUCT(kt, buf, st)                                          \
    {                                                                     \
      half8 xi = *(const half8*)(cxi + (kt) * 32);                        \
      half8 xj = *(const half8*)(cxj + (kt) * 32);                        \
      union { half8 h; unsigned u4[4]; } U;                               \
      U.h = xi - xj;                                                      \
      U.u4[0] &= 0x7FFF7FFFu; U.u4[1] &= 0x7FFF7FFFu;                     \
      U.u4[2] &= 0x7FFF7FFFu; U.u4[3] &= 0x7FFF7FFFu;                     \
      sA[buf][st][w][L] = U.h;                                            \
    }

  #define CONSUME(kt, buf, st)                                            \
    {                                                                     \
      half8 afr[4];                                                       \
      _Pragma("unroll")                                                   \
      for (int s = 0; s < 4; ++s) afr[s] = sA[buf][st][s][L];             \
      half8 bfr[4];                                                       \
      _Pragma("unroll")                                                   \
      for (int u = 0; u < 4; ++u)                                         \
        bfr[u] = *(const half8*)(bbase + (kt) * 8192 + u * 128);          \
      _Pragma("unroll")                                                   \
      for (int s = 0; s < 4; ++s)                                         \
        _Pragma("unroll")                                                 \
        for (int u = 0; u < 4; ++u)                                       \
          acc[s][u] = __builtin_amdgcn_mfma_f32_16x16x32_f16(             \
              afr[s], bfr[u], acc[s][u], 0, 0, 0);                        \
    }

  // prologue: chunk 0 (steps 0,1)
  CONSTRUCT(0, 0, 0)
  CONSTRUCT(1, 0, 1)
  __syncthreads();

  #pragma unroll 2
  for (int t = 0; t < 8; ++t) {
    const int buf = t & 1;
    CONSUME(2 * t, buf, 0)
    CONSUME(2 * t + 1, buf, 1)
    if (t < 7) {
      CONSTRUCT(2 * t + 2, 1 - buf, 0)
      CONSTRUCT(2 * t + 3, 1 - buf, 1)
    }
    __syncthreads();
  }
  #undef CONSTRUCT
  #undef CONSUME

  // ---- epilogue: + label rank-2 + b1, fast gelu, dot W2, reduce, sigmoid ----
  const int q = L >> 4;
  float w1l0[4], w1l1[4], bb1[4], ww2[4];
  #pragma unroll
  for (int u = 0; u < 4; ++u) {
    int n = w * 64 + u * 16 + nl;
    w1l0[u] = W1[512 * HDIM + n];
    w1l1[u] = W1[513 * HDIM + n];
    bb1[u] = b1[n];
    ww2[u] = W2[n];
  }
  #pragma unroll
  for (int s = 0; s < 4; ++s) {
    #pragma unroll
    for (int r = 0; r < 4; ++r) {
      int m = s * 16 + q * 4 + r;     // C/D: row = quad*4 + reg
      float l0v = sLab0[m], l1v = sLab1[m];
      float v = 0.f;
      #pragma unroll
      for (int u = 0; u < 4; ++u) {
        float e = acc[s][u][r] + l0v * w1l0[u] + l1v * w1l1[u] + bb1[u];
        v += gelu_fast(e) * ww2[u];
      }
      v += __shfl_xor(v, 1, 64);
      v += __shfl_xor(v, 2, 64);
      v += __shfl_xor(v, 4, 64);
      v += __shfl_xor(v, 8, 64);       // sum over 16 lanes of the quad
      if (nl == 0) sScore[m * 4 + w] = v;
    }
  }
  __syncthreads();
  if (tid < 64) {
    float s4 = sScore[tid * 4 + 0] + sScore[tid * 4 + 1] + sScore[tid * 4 + 2] +
               sScore[tid * 4 + 3] + b2[0];
    float hsv = fast_rcp(1.0f + __expf(-s4));
    int gi = i0 + (tid >> 3), gj = j0 + (tid & 7);
    out_hs[(size_t)gi * BN + gj] = hsv;
  }
}

// ---------------- row softmax of adj + TAU*log(hs + EPS) ----------------
__global__ __launch_bounds__(256) void softmax_kernel(const float* __restrict__ adj,
                                                      const float* __restrict__ hs,
                                                      float* __restrict__ out) {
  int i = blockIdx.x, t = threadIdx.x;
  __shared__ float redm[4];
  __shared__ float reds[4];
  float l[4];
  float mx = -1e30f;
  #pragma unroll
  for (int k = 0; k < 4; ++k) {
    int j = t + k * 256;
    float lv = adj[(size_t)i * BN + j] + TAUF * __logf(hs[(size_t)i * BN + j] + EPSF);
    l[k] = lv;
    mx = fmaxf(mx, lv);
  }
  #pragma unroll
  for (int o = 1; o <= 32; o <<= 1) mx = fmaxf(mx, __shfl_xor(mx, o, 64));
  if ((t & 63) == 0) redm[t >> 6] = mx;
  __syncthreads();
  mx = fmaxf(fmaxf(redm[0], redm[1]), fmaxf(redm[2], redm[3]));
  float ex[4];
  float se = 0.f;
  #pragma unroll
  for (int k = 0; k < 4; ++k) { ex[k] = __expf(l[k] - mx); se += ex[k]; }
  #pragma unroll
  for (int o = 1; o <= 32; o <<= 1) se += __shfl_xor(se, o, 64);
  if ((t & 63) == 0) reds[t >> 6] = se;
  __syncthreads();
  se = reds[0] + reds[1] + reds[2] + reds[3];
  float inv = fast_rcp(se);
  #pragma unroll
  for (int k = 0; k < 4; ++k) out[(size_t)i * BN + t + k * 256] = ex[k] * inv;
}

extern "C" void kernel_launch(void* const* d_in, const int* in_sizes, int n_in,
                              void* d_out, int out_size, void* d_ws, size_t ws_size,
                              hipStream_t stream) {
  (void)in_sizes; (void)n_in; (void)out_size; (void)ws_size;
  const float* X   = (const float*)d_in[0];
  const float* lg  = (const float*)d_in[1];
  const float* adj = (const float*)d_in[2];
  const float* W1  = (const float*)d_in[3];
  const float* b1  = (const float*)d_in[4];
  const float* W2  = (const float*)d_in[5];
  const float* b2  = (const float*)d_in[6];
  float* out = (float*)d_out;                       // [0,B^2): adj_refined, [B^2,2B^2): h_scores
  _Float16* w1h = (_Float16*)d_ws;                  // 512*256 fp16 = 256 KB
  float* oh = (float*)((char*)d_ws + FEATN * HDIM * 2);  // 1024*2 f32

  float* out_hs = out + (size_t)BN * BN;

  prep_kernel<<<dim3(68), dim3(256), 0, stream>>>(W1, lg, w1h, oh);
  gemm_kernel<<<dim3(128, 128), dim3(256), 0, stream>>>(X, w1h, oh, W1, b1, W2, b2, out_hs);
  softmax_kernel<<<dim3(BN), dim3(256), 0, stream>>>(adj, out_hs, out);
}